// Round 13
// baseline (253.182 us; speedup 1.0000x reference)
//
#include <hip/hip_runtime.h>
#include <math.h>

#define B_ 4
#define T_ 2048
#define E_ 1024
#define H_ 16
#define D_ 64

typedef __bf16 bf16_t;
typedef bf16_t bf16x8 __attribute__((ext_vector_type(8)));
typedef float  f32x4  __attribute__((ext_vector_type(4)));
typedef float  f32x16 __attribute__((ext_vector_type(16)));
typedef unsigned short u16x4 __attribute__((ext_vector_type(4)));
typedef unsigned int   u32x4 __attribute__((ext_vector_type(4)));

static __device__ __forceinline__ unsigned short f2bf(float f) {
    bf16_t h = (bf16_t)f;
    return __builtin_bit_cast(unsigned short, h);
}
static __device__ __forceinline__ unsigned int pk2(float a, float b) {
    return (unsigned int)f2bf(a) | ((unsigned int)f2bf(b) << 16);
}
// native 2^x (q is pre-scaled by 0.125*log2e so this computes e^(orig S))
static __device__ __forceinline__ float ex2(float x) {
    float r; asm("v_exp_f32 %0, %1" : "=v"(r) : "v"(x)); return r;
}
// v_permlane32_swap_b32: a' = {a.row0, b.row0}, b' = {a.row1, b.row1}
static __device__ __forceinline__ void pl32swap(unsigned int& a, unsigned int& b) {
    asm("v_permlane32_swap_b32 %0, %1" : "+v"(a), "+v"(b));
}

// async global->LDS, 16B per lane; lds base wave-uniform + lane*16
#define GLD(gp, lp) __builtin_amdgcn_global_load_lds( \
    (const __attribute__((address_space(1))) unsigned int*)(gp), \
    (__attribute__((address_space(3))) unsigned int*)(lp), 16, 0, 0)

#define BAR() __builtin_amdgcn_s_barrier()
#define WAIT_LGKM0() asm volatile("s_waitcnt lgkmcnt(0)" ::: "memory")
#define VMC(n) asm volatile("s_waitcnt vmcnt(" #n ")" ::: "memory")

// ---------------------------------------------------------------------------
// prep: fused x-cast (blocks 0..8191) + weight transpose-cast (blocks 8192+).
// grid 9216, block 256.
// ---------------------------------------------------------------------------
__global__ void prep_kernel(const float* __restrict__ xin, unsigned short* __restrict__ xb,
                            const float* __restrict__ Wq, const float* __restrict__ Wk,
                            const float* __restrict__ Wv, const float* __restrict__ Wp,
                            unsigned short* __restrict__ wf, unsigned short* __restrict__ wpt) {
    __shared__ unsigned short Ts[64 * 66];
    const int bid = blockIdx.x;
    const int tid = threadIdx.x;
    if (bid < 8192) {                 // cast x fp32 -> bf16, 4 elems/thread
        int i = bid * 256 + tid;
        float4 v = ((const float4*)xin)[i];
        ushort4 o;
        o.x = f2bf(v.x); o.y = f2bf(v.y); o.z = f2bf(v.z); o.w = f2bf(v.w);
        ((ushort4*)xb)[i] = o;
        return;
    }
    const int b2 = bid - 8192;        // 0..1023
    const int bx = b2 & 15, by = b2 >> 4;
    const int grp = by >> 4, yy = by & 15;
    const float* in; unsigned short* out; int yA, S;
    if (grp == 3) { in = Wp; out = wpt; yA = 64;    S = 1024; }
    else {
        in = (grp == 0) ? Wq : (grp == 1) ? Wk : Wv;
        out = wf + (size_t)grp * 1024 * 1024; yA = 65536; S = 64;
    }
    const int r = tid >> 2, c4 = tid & 3;
    const float* ip = in + (size_t)yA * yy + (size_t)(bx * 64 + r) * S + c4 * 16;
    #pragma unroll
    for (int j = 0; j < 4; ++j) {
        float4 v = *(const float4*)&ip[j * 4];
        Ts[(c4 * 16 + j * 4 + 0) * 66 + r] = f2bf(v.x);
        Ts[(c4 * 16 + j * 4 + 1) * 66 + r] = f2bf(v.y);
        Ts[(c4 * 16 + j * 4 + 2) * 66 + r] = f2bf(v.z);
        Ts[(c4 * 16 + j * 4 + 3) * 66 + r] = f2bf(v.w);
    }
    __syncthreads();
    unsigned short* op = out + (size_t)(yy * 64 + r) * 1024 + bx * 64 + c4 * 16;
    #pragma unroll
    for (int j = 0; j < 4; ++j) {
        u16x4 pk;
        #pragma unroll
        for (int m = 0; m < 4; ++m) pk[m] = Ts[r * 66 + c4 * 16 + j * 4 + m];
        *(u16x4*)&op[j * 4] = pk;
    }
}

// ---------------------------------------------------------------------------
// 128x256-tile 8-wave GEMM core (qkv + proj). m on fast grid axis for XCD L2
// locality (r9); staging ledger verified r8.
// ---------------------------------------------------------------------------

#define GEMM_CORE_DECLS \
    const int tid = threadIdx.x; \
    const int w = tid >> 6, lane = tid & 63; \
    const int wr = w >> 2, wc = w & 3; \
    const int l15 = lane & 15, quad = lane >> 4, lsw = l15 & 7; \
    const int rowg = lane >> 3; \
    const int swz = ((lane & 7) ^ rowg) * 8; \
    f32x4 acc[4][4]; \
    _Pragma("unroll") for (int i_ = 0; i_ < 4; ++i_) \
        _Pragma("unroll") for (int j_ = 0; j_ < 4; ++j_) \
            acc[i_][j_] = (f32x4){0.f, 0.f, 0.f, 0.f};

#define MFMA_P(nb) \
    __builtin_amdgcn_s_setprio(1); \
    _Pragma("unroll") for (int m_ = 0; m_ < 4; ++m_) \
        _Pragma("unroll") for (int j_ = 0; j_ < 2; ++j_) \
            _Pragma("unroll") for (int k_ = 0; k_ < 2; ++k_) \
                acc[m_][(nb) + j_] = __builtin_amdgcn_mfma_f32_16x16x32_bf16( \
                    fA[m_][k_], fB[(nb) + j_][k_], acc[m_][(nb) + j_], 0, 0, 0); \
    __builtin_amdgcn_s_setprio(0);

#define GEMM_K_LOOP \
    stageA(0, 0); stageA(0, 1); stageB(0, 0, 0); stageB(0, 0, 1); \
    stageB(0, 1, 0); stageB(0, 1, 1); \
    stageA(1, 0); stageA(1, 1); stageB(1, 0, 0); stageB(1, 0, 1); \
    VMC(6); BAR(); \
    _Pragma("unroll 1") \
    for (int it = 0; it < 8; ++it) { \
        const int t0 = 2 * it, t1 = 2 * it + 1; \
        const bool more = it < 7; \
        bf16x8 fA[4][2], fB[4][2]; \
        /* P1: reads fA(t0)+fBlo(t0); stage Bh(t1) */ \
        _Pragma("unroll") for (int m_ = 0; m_ < 4; ++m_) { fA[m_][0] = rdA(t0, m_, 0); fA[m_][1] = rdA(t0, m_, 1); } \
        _Pragma("unroll") for (int n_ = 0; n_ < 2; ++n_) { fB[n_][0] = rdB(t0, n_, 0); fB[n_][1] = rdB(t0, n_, 1); } \
        stageB(t1, 1, 0); stageB(t1, 1, 1); \
        BAR(); WAIT_LGKM0(); \
        MFMA_P(0); \
        VMC(6); BAR(); \
        /* P2: reads fBhi(t0); stage A(t0+2), Bl(t0+2) */ \
        _Pragma("unroll") for (int n_ = 0; n_ < 2; ++n_) { fB[2 + n_][0] = rdB(t0, 2 + n_, 0); fB[2 + n_][1] = rdB(t0, 2 + n_, 1); } \
        if (more) { stageA(t0 + 2, 0); stageA(t0 + 2, 1); stageB(t0 + 2, 0, 0); stageB(t0 + 2, 0, 1); } \
        BAR(); WAIT_LGKM0(); \
        MFMA_P(2); \
        if (more) { VMC(6); } else { VMC(2); } \
        BAR(); \
        /* P3: reads fA(t1)+fBlo(t1); stage Bh(t0+2) */ \
        _Pragma("unroll") for (int m_ = 0; m_ < 4; ++m_) { fA[m_][0] = rdA(t1, m_, 0); fA[m_][1] = rdA(t1, m_, 1); } \
        _Pragma("unroll") for (int n_ = 0; n_ < 2; ++n_) { fB[n_][0] = rdB(t1, n_, 0); fB[n_][1] = rdB(t1, n_, 1); } \
        if (more) { stageB(t0 + 2, 1, 0); stageB(t0 + 2, 1, 1); } \
        BAR(); WAIT_LGKM0(); \
        MFMA_P(0); \
        if (more) { VMC(6); } else { VMC(0); } \
        BAR(); \
        /* P4: reads fBhi(t1); stage A(t1+2), Bl(t1+2) */ \
        _Pragma("unroll") for (int n_ = 0; n_ < 2; ++n_) { fB[2 + n_][0] = rdB(t1, 2 + n_, 0); fB[2 + n_][1] = rdB(t1, 2 + n_, 1); } \
        if (more) { stageA(t1 + 2, 0); stageA(t1 + 2, 1); stageB(t1 + 2, 0, 0); stageB(t1 + 2, 0, 1); } \
        BAR(); WAIT_LGKM0(); \
        MFMA_P(2); \
        if (more) { VMC(6); } \
        BAR(); \
    }

// ---------------------------------------------------------------------------
// Fused QKV GEMM: [8192 x 1024] x [3072 x 1024]^T, 128x256 tiles.
// q scaled 0.125*log2e (+bias); k +bias; v (+bias) transposed [bh][64][T].
// grid 768 (1D, m fast), block 512.
// ---------------------------------------------------------------------------
__global__ __launch_bounds__(512, 2) void qkv_gemm(
    const unsigned short* __restrict__ xb,
    const unsigned short* __restrict__ wf,
    const float* __restrict__ bq, const float* __restrict__ bk, const float* __restrict__ bv,
    unsigned short* __restrict__ qo, unsigned short* __restrict__ ko,
    unsigned short* __restrict__ vt)
{
    __shared__ __align__(16) unsigned short sm[49152];   // 96 KiB

    const int bid = blockIdx.x;
    const int m0 = (bid & 63) * 128;
    const int n0 = (bid >> 6) * 256;

    GEMM_CORE_DECLS

    auto stageA = [&](int t, int g) {
        const int rb = w * 16 + g * 8;
        unsigned short* dst = sm + (t & 1) * 24576 + rb * 64;
        GLD(xb + (size_t)(m0 + rb + rowg) * 1024 + t * 64 + swz, dst);
    };
    auto stageB = [&](int t, int R, int g) {
        const int rb = w * 16 + g * 8;
        const int ar0 = (rb >> 5) * 64 + R * 32 + (rb & 31);
        unsigned short* dst = sm + (t & 1) * 24576 + 8192 + ar0 * 64;
        GLD(wf + (size_t)(n0 + ar0 + rowg) * 1024 + t * 64 + swz, dst);
    };
    auto rdA = [&](int t, int fm, int ks) {
        const int row = wr * 64 + fm * 16 + l15;
        return *(const bf16x8*)&sm[(t & 1) * 24576 + row * 64 + (((ks * 4 + quad) ^ lsw) * 8)];
    };
    auto rdB = [&](int t, int fn, int ks) {
        const int row = wc * 64 + fn * 16 + l15;
        return *(const bf16x8*)&sm[(t & 1) * 24576 + 8192 + row * 64 + (((ks * 4 + quad) ^ lsw) * 8)];
    };

    GEMM_K_LOOP

    const int which = n0 >> 10;           // q / k / v
    const int nb = n0 & 1023;
    if (which < 2) {
        const float* bias = which ? bk : bq;
        unsigned short* outp = which ? ko : qo;
        const float sc = which ? 1.f : 0.125f * 1.44269504088896f;
        #pragma unroll
        for (int fm = 0; fm < 4; ++fm)
            #pragma unroll
            for (int fn = 0; fn < 4; ++fn) {
                int colg = nb + wc * 64 + fn * 16 + l15;
                int h = colg >> 6, d = colg & 63;
                float bi = bias[colg];
                #pragma unroll
                for (int r = 0; r < 4; ++r) {
                    int row = m0 + wr * 64 + fm * 16 + quad * 4 + r;
                    int b = row >> 11, t = row & 2047;
                    outp[(((size_t)b * 16 + h) * 2048 + t) * 64 + d] = f2bf((acc[fm][fn][r] + bi) * sc);
                }
            }
    } else {
        // V: transpose via LDS, 2 sub-blocks of 128(n) x 128(m), stride 136
        const int b = m0 >> 11, t0r = m0 & 2047;
        for (int nh = 0; nh < 2; ++nh) {
            __syncthreads();
            if ((wc >> 1) == nh) {
                const int cc = wc & 1;
                #pragma unroll
                for (int fm = 0; fm < 4; ++fm)
                    #pragma unroll
                    for (int fn = 0; fn < 4; ++fn) {
                        int colL = cc * 64 + fn * 16 + l15;          // 0..127
                        int colg = nb + nh * 128 + colL;
                        float bi = bv[colg];
                        u16x4 pk;
                        #pragma unroll
                        for (int r = 0; r < 4; ++r) pk[r] = f2bf(acc[fm][fn][r] + bi);
                        *(u16x4*)&sm[colL * 136 + wr * 64 + fm * 16 + quad * 4] = pk;
                    }
            }
            __syncthreads();
            const int nl = tid >> 2, tq = tid & 3;                   // col 0..127
            const int colg = nb + nh * 128 + nl;
            const int h = colg >> 6, d = colg & 63;
            unsigned short* dst = vt + (((size_t)b * 16 + h) * 64 + d) * 2048 + t0r + tq * 32;
            #pragma unroll
            for (int j = 0; j < 4; ++j)
                *(float4*)&dst[j * 8] = *(const float4*)&sm[nl * 136 + tq * 32 + j * 8];
        }
    }
}

// ---------------------------------------------------------------------------
// Output projection: A = att2 bf16 [b*16+h][t][64] (gathered), B = Wp^T,
// fp32 out + bias. 128x256 tiles, same core. grid 256 (1D, m fast), block 512.
// ---------------------------------------------------------------------------
__global__ __launch_bounds__(512, 2) void proj_gemm(
    const unsigned short* __restrict__ A,
    const unsigned short* __restrict__ wpt,
    const float* __restrict__ bp,
    float* __restrict__ out)
{
    __shared__ __align__(16) unsigned short sm[49152];   // 96 KiB

    const int bid = blockIdx.x;
    const int m0 = (bid & 63) * 128;
    const int n0 = (bid >> 6) * 256;

    GEMM_CORE_DECLS

    const unsigned short* Ab = A + (size_t)(m0 >> 11) * 16 * 131072 + (size_t)(m0 & 2047) * 64;
    auto stageA = [&](int t, int g) {
        const int rb = w * 16 + g * 8;
        unsigned short* dst = sm + (t & 1) * 24576 + rb * 64;
        GLD(Ab + (size_t)t * 131072 + (rb + rowg) * 64 + swz, dst);
    };
    auto stageB = [&](int t, int R, int g) {
        const int rb = w * 16 + g * 8;
        const int ar0 = (rb >> 5) * 64 + R * 32 + (rb & 31);
        unsigned short* dst = sm + (t & 1) * 24576 + 8192 + ar0 * 64;
        GLD(wpt + (size_t)(n0 + ar0 + rowg) * 1024 + t * 64 + swz, dst);
    };
    auto rdA = [&](int t, int fm, int ks) {
        const int row = wr * 64 + fm * 16 + l15;
        return *(const bf16x8*)&sm[(t & 1) * 24576 + row * 64 + (((ks * 4 + quad) ^ lsw) * 8)];
    };
    auto rdB = [&](int t, int fn, int ks) {
        const int row = wc * 64 + fn * 16 + l15;
        return *(const bf16x8*)&sm[(t & 1) * 24576 + 8192 + row * 64 + (((ks * 4 + quad) ^ lsw) * 8)];
    };

    GEMM_K_LOOP

    #pragma unroll
    for (int fm = 0; fm < 4; ++fm)
        #pragma unroll
        for (int fn = 0; fn < 4; ++fn) {
            int col = n0 + wc * 64 + fn * 16 + l15;
            float bi = bp[col];
            #pragma unroll
            for (int r = 0; r < 4; ++r) {
                int row = m0 + wr * 64 + fm * 16 + quad * 4 + r;
                out[(size_t)row * 1024 + col] = acc[fm][fn][r] + bi;
            }
        }
}

// ---------------------------------------------------------------------------
// Flash attention v6b: KVBLK=64, 32KB LDS. Structure CORRECTNESS-VERIFIED in
// r11 (passed, absmax 0.0078); r11's regression was solely the forced
// __launch_bounds__(512,8) capping VGPR below live state (VGPR 32, scratch
// spills, 1.43GB FETCH). Fix: (512,4) non-forcing bound -> allocator free to
// ~64 VGPR naturally (v5 with MORE state = exactly 64). If VGPR<=64, HW
// schedules 4 blocks/CU (32KB LDS, 8 waves/SIMD) -> 2x occupancy vs v5.
// Block 512 thr = 8 waves = 4 q-groups(32q) x 2 key-halves over 128 queries.
// Per trip per wave: 1 QK^T subtile (4 MFMA), 16 exp, 4+2 PV/Osum MFMA.
// K/V staged once per block (1 GLD each per wave). Two-pass leg-end merge.
// grid (64 bh, 8 pairs), trips 2p+2 legs-paired -> 34/block uniform.
// C/D layout (verified): col=lane&31, row=(reg&3)+8*(reg>>2)+4*(lane>>5).
// ---------------------------------------------------------------------------
__global__ __launch_bounds__(512, 4) void attn_kernel(
    const unsigned short* __restrict__ q, const unsigned short* __restrict__ k,
    const unsigned short* __restrict__ vt, unsigned short* __restrict__ att2)
{
    __shared__ __align__(16) unsigned short KV[2][2][4096];   // [buf][K|V] 32KB

    const int tid = threadIdx.x;
    const int w = tid >> 6, lane = tid & 63;
    const int l31 = lane & 31, h = lane >> 5;
    const int qg2 = w >> 1, ksel = w & 1;     // q-group 0..3, key-half 0..1
    const int bh = blockIdx.x;
    const int rs = l31 & 7;

    const unsigned short* kb = k  + (size_t)bh * 2048 * 64;
    const unsigned short* vb = vt + (size_t)bh * 64 * 2048;

    // ones B-fragment for Osum = P . 1 (row-sums of P in O's C-layout)
    u32x4 onesu; onesu[0] = onesu[1] = onesu[2] = onesu[3] = 0x3F803F80u;
    const bf16x8 bOnes = __builtin_bit_cast(bf16x8, onesu);

    // staging (wave w: rows/d-rows 8w+rg, rg=lane>>3; slot lane&7 <- chunk ^rg)
    const int rg = lane >> 3;
    const size_t kOff = (size_t)(8 * w + rg) * 64 + (size_t)(((lane & 7) ^ rg) * 8);
    const size_t vOff = (size_t)(8 * w + rg) * 2048 + (size_t)(((lane & 7) ^ rg) * 8);

    auto stage = [&](int jt, int buf) {
        GLD(kb + kOff + (size_t)jt * 4096, &KV[buf][0][w * 512]);
        GLD(vb + vOff + jt * 64,           &KV[buf][1][w * 512]);
    };

    for (int leg = 0; leg < 2; ++leg) {
        const int qtile = leg ? (15 - (int)blockIdx.y) : (int)blockIdx.y;
        const int qb0 = qtile * 128;
        const int qmin = qb0 + qg2 * 32, qmax = qmin + 31;
        const int qg = qmin + l31;             // query owned as S^T COLUMN
        const int trips = 2 * qtile + 2;       // 64-key tiles

        // Q B-fragments straight from global: B[k=d][n=query]
        bf16x8 fQ[4];
        {
            const unsigned short* qp = q + ((size_t)bh * 2048 + qg) * 64 + h * 8;
            #pragma unroll
            for (int ks = 0; ks < 4; ++ks) fQ[ks] = *(const bf16x8*)&qp[ks * 16];
        }

        f32x16 O[2], Osum;
        #pragma unroll
        for (int nt = 0; nt < 2; ++nt)
            #pragma unroll
            for (int i = 0; i < 16; ++i) O[nt][i] = 0.f;
        #pragma unroll
        for (int i = 0; i < 16; ++i) Osum[i] = 0.f;

        stage(0, 0);
        VMC(0);
        BAR();

        for (int jt = 0; jt < trips; ++jt) {
            const int buf = jt & 1;
            if (jt + 1 < trips) stage(jt + 1, buf ^ 1);
            const unsigned short* Ks = KV[buf][0];
            const unsigned short* Vs = KV[buf][1];
            const int wk0 = jt * 64 + 32 * ksel;     // wave's 32-key base

            if (wk0 <= qmax) {                       // wave-uniform causal skip
                // QK^T: S = K(32 rows) . Q^T, 4 MFMA over d
                f32x16 S;
                #pragma unroll
                for (int i = 0; i < 16; ++i) S[i] = 0.f;
                __builtin_amdgcn_s_setprio(1);
                {
                    const int row = 32 * ksel + l31;
                    #pragma unroll
                    for (int ks = 0; ks < 4; ++ks) {
                        bf16x8 aK = *(const bf16x8*)&Ks[row * 64 + (((2 * ks + h) ^ rs) * 8)];
                        S = __builtin_amdgcn_mfma_f32_32x32x16_bf16(aK, fQ[ks], S, 0, 0, 0);
                    }
                }
                __builtin_amdgcn_s_setprio(0);

                // softmax (native 2^x): element 4g+r -> key wk0+8g+4h+r
                const bool nm = (wk0 + 31) > qmin;
                unsigned int e0[4], e1[4];
                #pragma unroll
                for (int g = 0; g < 4; ++g) {
                    float p[4];
                    #pragma unroll
                    for (int r = 0; r < 4; ++r) {
                        float pv = ex2(S[4 * g + r]);
                        if (nm) {
                            int key = wk0 + 8 * g + 4 * h + r;
                            if (key > qg) pv = 0.f;
                        }
                        p[r] = pv;
                    }
                    e0[g] = pk2(p[0], p[1]);
                    e1[g] = pk2(p[2], p[3]);
                }

                // PV + Osum: slices s=0,1 cover keys wk0+16s+8h+{0..7}
                __builtin_amdgcn_s_setprio(1);
                #pragma unroll
                for (int s = 0; s < 2; ++s) {
                    unsigned int a = e0[2 * s], b = e0[2 * s + 1];
                    pl32swap(a, b);                       // a={keys+0,+1}, b={+4,+5}
                    unsigned int c2 = e1[2 * s], d2 = e1[2 * s + 1];
                    pl32swap(c2, d2);                     // c2={+2,+3}, d2={+6,+7}
                    u32x4 t; t[0] = a; t[1] = c2; t[2] = b; t[3] = d2;
                    bf16x8 aP = __builtin_bit_cast(bf16x8, t);
                    const int cb = 4 * ksel + 2 * s;      // V chunk c = cb + h
                    #pragma unroll
                    for (int nt = 0; nt < 2; ++nt) {
                        const int drow = nt * 32 + l31;
                        bf16x8 bV = *(const bf16x8*)&Vs[drow * 64 + (((cb + h) ^ rs) * 8)];
                        O[nt] = __builtin_amdgcn_mfma_f32_32x32x16_bf16(aP, bV, O[nt], 0, 0, 0);
                    }
                    Osum = __builtin_amdgcn_mfma_f32_32x32x16_bf16(aP, bOnes, Osum, 0, 0, 0);
                }
                __builtin_amdgcn_s_setprio(0);
            }

            VMC(0);   // next tile landed
            BAR();
        }

        // -------- two-pass merge of key-halves via freed KV LDS (24KB/pass)
        float* Lf = (float*)KV;
        for (int half = 0; half < 2; ++half) {
            __syncthreads();
            float* mb = Lf + (size_t)(qg2 & 1) * 48 * 64;
            if ((qg2 >> 1) == half && ksel) {
                #pragma unroll
                for (int nt = 0; nt < 2; ++nt)
                    #pragma unroll
                    for (int i = 0; i < 16; ++i)
                        mb[(nt * 16 + i) * 64 + lane] = O[nt][i];
                #pragma unroll
                for (int i = 0; i < 16; ++i)
                    mb[(32 + i) * 64 + lane] = Osum[i];
            }
            __syncthreads();
            if ((qg2 >> 1) == half && !ksel) {
                #pragma unroll
                for (int nt = 0; nt < 2; ++nt)
                    #pragma unroll
                    for (int i = 0; i < 16; ++i)
                        O[nt][i] += mb[(nt * 16 + i) * 64 + lane];
                #pragma unroll
                for (int i = 0; i < 16; ++i)
                    Osum[i] += mb[(32 + i) * 64 + lane];

                // O[nt][4g+r]: query row 8g+4h+r, d col nt*32+l31
                unsigned short* ob = att2 + ((size_t)bh * 2048 + qmin) * 64;
                #pragma unroll
                for (int g = 0; g < 4; ++g)
                    #pragma unroll
                    for (int r = 0; r < 4; ++r) {
                        const float iv = 1.f / Osum[4 * g + r];
                        const int qy = 8 * g + 4 * h + r;
                        #pragma unroll
                        for (int nt = 0; nt < 2; ++nt)
                            ob[(size_t)qy * 64 + nt * 32 + l31] = f2bf(O[nt][4 * g + r] * iv);
                    }
            }
        }
        __syncthreads();   // protect merge reads from next leg's staging
    }
}

extern "C" void kernel_launch(void* const* d_in, const int* in_sizes, int n_in,
                              void* d_out, int out_size, void* d_ws, size_t ws_size,
                              hipStream_t stream) {
    const float* x  = (const float*)d_in[0];
    const float* Wq = (const float*)d_in[1];
    const float* Wk = (const float*)d_in[2];
    const float* Wv = (const float*)d_in[3];
    const float* bq = (const float*)d_in[4];
    const float* bk = (const float*)d_in[5];
    const float* bv = (const float*)d_in[6];
    const float* Wp = (const float*)d_in[7];
    const float* bp = (const float*)d_in[8];
    float* out = (float*)d_out;

    const size_t nx = (size_t)B_ * T_ * E_;
    unsigned short* base = (unsigned short*)d_ws;
    unsigned short* xb  = base;
    unsigned short* qb  = xb + nx;
    unsigned short* kb  = qb + nx;
    unsigned short* vtb = kb + nx;
    unsigned short* atb = vtb + nx;          // [bh][t][64]
    unsigned short* wf  = atb + nx;          // [3072][1024]
    unsigned short* wpt = wf + 3072 * 1024;  // [1024][1024]

    prep_kernel<<<9216, 256, 0, stream>>>(x, xb, Wq, Wk, Wv, Wp, wf, wpt);
    qkv_gemm<<<768, 512, 0, stream>>>(xb, wf, bq, bk, bv, qb, kb, vtb);
    attn_kernel<<<dim3(64, 8), 512, 0, stream>>>(qb, kb, vtb, atb);
    proj_gemm<<<256, 512, 0, stream>>>(atb, wpt, bp, out);
}

// Round 14
// 242.903 us; speedup vs baseline: 1.0423x; 1.0423x over previous
//
#include <hip/hip_runtime.h>
#include <math.h>

#define B_ 4
#define T_ 2048
#define E_ 1024
#define H_ 16
#define D_ 64

typedef __bf16 bf16_t;
typedef bf16_t bf16x8 __attribute__((ext_vector_type(8)));
typedef float  f32x4  __attribute__((ext_vector_type(4)));
typedef float  f32x16 __attribute__((ext_vector_type(16)));
typedef unsigned short u16x4 __attribute__((ext_vector_type(4)));
typedef unsigned int   u32x4 __attribute__((ext_vector_type(4)));

static __device__ __forceinline__ unsigned short f2bf(float f) {
    bf16_t h = (bf16_t)f;
    return __builtin_bit_cast(unsigned short, h);
}
static __device__ __forceinline__ unsigned int pk2(float a, float b) {
    return (unsigned int)f2bf(a) | ((unsigned int)f2bf(b) << 16);
}
// native 2^x (q is pre-scaled by 0.125*log2e so this computes e^(orig S))
static __device__ __forceinline__ float ex2(float x) {
    float r; asm("v_exp_f32 %0, %1" : "=v"(r) : "v"(x)); return r;
}
// v_permlane32_swap_b32: a' = {a.row0, b.row0}, b' = {a.row1, b.row1}
static __device__ __forceinline__ void pl32swap(unsigned int& a, unsigned int& b) {
    asm("v_permlane32_swap_b32 %0, %1" : "+v"(a), "+v"(b));
}

// async global->LDS, 16B per lane; lds base wave-uniform + lane*16
#define GLD(gp, lp) __builtin_amdgcn_global_load_lds( \
    (const __attribute__((address_space(1))) unsigned int*)(gp), \
    (__attribute__((address_space(3))) unsigned int*)(lp), 16, 0, 0)

#define BAR() __builtin_amdgcn_s_barrier()
#define WAIT_LGKM0() asm volatile("s_waitcnt lgkmcnt(0)" ::: "memory")
#define VMC(n) asm volatile("s_waitcnt vmcnt(" #n ")" ::: "memory")

// ---------------------------------------------------------------------------
// prep: fused x-cast (blocks 0..8191) + weight transpose-cast (blocks 8192+).
// grid 9216, block 256.
// ---------------------------------------------------------------------------
__global__ void prep_kernel(const float* __restrict__ xin, unsigned short* __restrict__ xb,
                            const float* __restrict__ Wq, const float* __restrict__ Wk,
                            const float* __restrict__ Wv, const float* __restrict__ Wp,
                            unsigned short* __restrict__ wf, unsigned short* __restrict__ wpt) {
    __shared__ unsigned short Ts[64 * 66];
    const int bid = blockIdx.x;
    const int tid = threadIdx.x;
    if (bid < 8192) {                 // cast x fp32 -> bf16, 4 elems/thread
        int i = bid * 256 + tid;
        float4 v = ((const float4*)xin)[i];
        ushort4 o;
        o.x = f2bf(v.x); o.y = f2bf(v.y); o.z = f2bf(v.z); o.w = f2bf(v.w);
        ((ushort4*)xb)[i] = o;
        return;
    }
    const int b2 = bid - 8192;        // 0..1023
    const int bx = b2 & 15, by = b2 >> 4;
    const int grp = by >> 4, yy = by & 15;
    const float* in; unsigned short* out; int yA, S;
    if (grp == 3) { in = Wp; out = wpt; yA = 64;    S = 1024; }
    else {
        in = (grp == 0) ? Wq : (grp == 1) ? Wk : Wv;
        out = wf + (size_t)grp * 1024 * 1024; yA = 65536; S = 64;
    }
    const int r = tid >> 2, c4 = tid & 3;
    const float* ip = in + (size_t)yA * yy + (size_t)(bx * 64 + r) * S + c4 * 16;
    #pragma unroll
    for (int j = 0; j < 4; ++j) {
        float4 v = *(const float4*)&ip[j * 4];
        Ts[(c4 * 16 + j * 4 + 0) * 66 + r] = f2bf(v.x);
        Ts[(c4 * 16 + j * 4 + 1) * 66 + r] = f2bf(v.y);
        Ts[(c4 * 16 + j * 4 + 2) * 66 + r] = f2bf(v.z);
        Ts[(c4 * 16 + j * 4 + 3) * 66 + r] = f2bf(v.w);
    }
    __syncthreads();
    unsigned short* op = out + (size_t)(yy * 64 + r) * 1024 + bx * 64 + c4 * 16;
    #pragma unroll
    for (int j = 0; j < 4; ++j) {
        u16x4 pk;
        #pragma unroll
        for (int m = 0; m < 4; ++m) pk[m] = Ts[r * 66 + c4 * 16 + j * 4 + m];
        *(u16x4*)&op[j * 4] = pk;
    }
}

// ---------------------------------------------------------------------------
// Fused QKV GEMM v2: 128x256 tile, BK=32, 48KB LDS (2x24KB dbuf) -> 2
// blocks/CU (cross-block barrier overlap, m114). 512 thr, 8 waves 2Mx4N,
// per-wave 64x64 (acc[4][4]). Per K-tile (32 total) 2 phases split by fm:
//   Phase A(t): read fB[0..3] (4 b128) + fA[0..1] (2); 8 MFMA (fm0-1 x fn0-3)
//   Phase B(t): read fA[2..3] (2); 8 MFMA (fm2-3 x fn0-3)
// T2 swizzle (rule 21): LDS granule (row,slot) holds global K-chunk
// slot^(row&3); linear GLD dest (granule g: row=g>>2, slot=g&3), inverse-
// swizzled global source; read slot = quad^(l15&3) -> permutation of linear
// 1KB read, conflict-free.
// STAGING LEDGER (block-wide read map: B(t) all rows last read @A(t); A(t)
// fm0-1 rows @A(t), fm2-3 rows @B(t)):
//   prologue: A(0),B0(0),B1(0),A(1),B0(1),B1(1); vmcnt(3) [A0,B(0) landed]
//   @A(t), 1<=t<31: stage A(t+1)  [A(t-1) last read @B(t-1), 1 bar gap]
//   @B(t), t<30:    stage B0,B1(t+2) [B(t) last read @A(t), 1 bar gap]
//   end-of-B(t) vmcnt(2): keeps newest 2 (B(t+2)) -> A(t+1) (@A(t)) and
//   B(t+1) (@B(t-1), older) landed before phase A(t+1) reads them.
//   Tail: end-B(30) vmcnt(0) drains A(31)+B(31); t=31 no stages/waits.
// q scaled 0.125*log2e (+bias); k +bias; v (+bias) transposed [bh][64][T].
// grid 768 (1D, m fast: XCD L2 locality, r9), block 512.
// ---------------------------------------------------------------------------
__global__ __launch_bounds__(512, 2) void qkv_gemm(
    const unsigned short* __restrict__ xb,
    const unsigned short* __restrict__ wf,
    const float* __restrict__ bq, const float* __restrict__ bk, const float* __restrict__ bv,
    unsigned short* __restrict__ qo, unsigned short* __restrict__ ko,
    unsigned short* __restrict__ vt)
{
    // buffer q at sm + q*12288 (u16): A[128][32] @0 (4096), B[256][32] @4096
    __shared__ __align__(16) unsigned short sm[24576];   // 48 KiB

    const int tid = threadIdx.x;
    const int w = tid >> 6, lane = tid & 63;
    const int wr = w >> 2, wc = w & 3;
    const int l15 = lane & 15, quad = lane >> 4;
    const int lsw3 = l15 & 3;
    const int m0 = (blockIdx.x & 63) * 128;
    const int n0 = (blockIdx.x >> 6) * 256;

    f32x4 acc[4][4];
    #pragma unroll
    for (int i = 0; i < 4; ++i)
        #pragma unroll
        for (int j = 0; j < 4; ++j) acc[i][j] = (f32x4){0.f, 0.f, 0.f, 0.f};

    // staging addresses (granule = tid): row = tid>>2, chunk = (tid&3)^(row&3)
    const int arow = tid >> 2;
    const int achk = (tid & 3) ^ (arow & 3);
    const unsigned short* Agb = xb + (size_t)(m0 + arow) * 1024 + achk * 8;
    const unsigned short* Bgb0 = wf + (size_t)(n0 + arow) * 1024 + achk * 8;        // rows 0-127
    const unsigned short* Bgb1 = wf + (size_t)(n0 + 128 + arow) * 1024 + achk * 8;  // rows 128-255

    auto stageA = [&](int t) {
        GLD(Agb + t * 32, sm + (t & 1) * 12288 + tid * 8);
    };
    auto stageB = [&](int t, int half) {
        GLD((half ? Bgb1 : Bgb0) + t * 32,
            sm + (t & 1) * 12288 + 4096 + (half * 512 + tid) * 8);
    };
    // reads: slot quad of row r lives at slot quad^(r&3); r&3 == l15&3
    auto rdA = [&](int t, int fm) {
        const int row = wr * 64 + fm * 16 + l15;
        return *(const bf16x8*)&sm[(t & 1) * 12288 + row * 32 + ((quad ^ lsw3) * 8)];
    };
    auto rdB = [&](int t, int fn) {
        const int row = wc * 64 + fn * 16 + l15;
        return *(const bf16x8*)&sm[(t & 1) * 12288 + 4096 + row * 32 + ((quad ^ lsw3) * 8)];
    };

    // prologue: tiles 0,1 fully staged
    stageA(0); stageB(0, 0); stageB(0, 1);
    stageA(1); stageB(1, 0); stageB(1, 1);
    VMC(3); BAR();

    #pragma unroll 1
    for (int t = 0; t < 32; ++t) {
        bf16x8 fB[4], fA0, fA1;
        // ---- Phase A: read all fB(t) + fA0,1(t); stage A(t+1)
        #pragma unroll
        for (int n = 0; n < 4; ++n) fB[n] = rdB(t, n);
        fA0 = rdA(t, 0); fA1 = rdA(t, 1);
        if (t >= 1 && t < 31) stageA(t + 1);
        BAR(); WAIT_LGKM0();
        __builtin_amdgcn_s_setprio(1);
        #pragma unroll
        for (int n = 0; n < 4; ++n) {
            acc[0][n] = __builtin_amdgcn_mfma_f32_16x16x32_bf16(fA0, fB[n], acc[0][n], 0, 0, 0);
            acc[1][n] = __builtin_amdgcn_mfma_f32_16x16x32_bf16(fA1, fB[n], acc[1][n], 0, 0, 0);
        }
        __builtin_amdgcn_s_setprio(0);
        BAR();

        // ---- Phase B: read fA2,3(t); stage B(t+2); vmcnt(2) covers t+1
        fA0 = rdA(t, 2); fA1 = rdA(t, 3);
        if (t < 30) { stageB(t + 2, 0); stageB(t + 2, 1); }
        BAR(); WAIT_LGKM0();
        __builtin_amdgcn_s_setprio(1);
        #pragma unroll
        for (int n = 0; n < 4; ++n) {
            acc[2][n] = __builtin_amdgcn_mfma_f32_16x16x32_bf16(fA0, fB[n], acc[2][n], 0, 0, 0);
            acc[3][n] = __builtin_amdgcn_mfma_f32_16x16x32_bf16(fA1, fB[n], acc[3][n], 0, 0, 0);
        }
        __builtin_amdgcn_s_setprio(0);
        if (t < 30) { VMC(2); } else if (t == 30) { VMC(0); }
        BAR();
    }

    const int which = n0 >> 10;           // q / k / v
    const int nb = n0 & 1023;
    if (which < 2) {
        const float* bias = which ? bk : bq;
        unsigned short* outp = which ? ko : qo;
        const float sc = which ? 1.f : 0.125f * 1.44269504088896f;
        #pragma unroll
        for (int fm = 0; fm < 4; ++fm)
            #pragma unroll
            for (int fn = 0; fn < 4; ++fn) {
                int colg = nb + wc * 64 + fn * 16 + l15;
                int h = colg >> 6, d = colg & 63;
                float bi = bias[colg];
                #pragma unroll
                for (int r = 0; r < 4; ++r) {
                    int row = m0 + wr * 64 + fm * 16 + quad * 4 + r;
                    int b = row >> 11, t = row & 2047;
                    outp[(((size_t)b * 16 + h) * 2048 + t) * 64 + d] = f2bf((acc[fm][fn][r] + bi) * sc);
                }
            }
    } else {
        // V: transpose via LDS, 2 sub-blocks of 128(n) x 128(m), stride 136
        // (reuses sm; 128*136*2B = 34KB > 24KB buffer0 -> spans both, fine
        // since K-loop is complete)
        const int b = m0 >> 11, t0r = m0 & 2047;
        for (int nh = 0; nh < 2; ++nh) {
            __syncthreads();
            if ((wc >> 1) == nh) {
                const int cc = wc & 1;
                #pragma unroll
                for (int fm = 0; fm < 4; ++fm)
                    #pragma unroll
                    for (int fn = 0; fn < 4; ++fn) {
                        int colL = cc * 64 + fn * 16 + l15;          // 0..127
                        int colg = nb + nh * 128 + colL;
                        float bi = bv[colg];
                        u16x4 pk;
                        #pragma unroll
                        for (int r = 0; r < 4; ++r) pk[r] = f2bf(acc[fm][fn][r] + bi);
                        *(u16x4*)&sm[colL * 136 + wr * 64 + fm * 16 + quad * 4] = pk;
                    }
            }
            __syncthreads();
            const int nl = tid >> 2, tq = tid & 3;                   // col 0..127
            const int colg = nb + nh * 128 + nl;
            const int h = colg >> 6, d = colg & 63;
            unsigned short* dst = vt + (((size_t)b * 16 + h) * 64 + d) * 2048 + t0r + tq * 32;
            #pragma unroll
            for (int j = 0; j < 4; ++j)
                *(float4*)&dst[j * 8] = *(const float4*)&sm[nl * 136 + tq * 32 + j * 8];
        }
    }
}

// ---------------------------------------------------------------------------
// 128x256-tile 8-wave GEMM core for proj (unchanged r9 structure).
// ---------------------------------------------------------------------------

#define GEMM_CORE_DECLS \
    const int tid = threadIdx.x; \
    const int w = tid >> 6, lane = tid & 63; \
    const int wr = w >> 2, wc = w & 3; \
    const int l15 = lane & 15, quad = lane >> 4, lsw = l15 & 7; \
    const int rowg = lane >> 3; \
    const int swz = ((lane & 7) ^ rowg) * 8; \
    f32x4 acc[4][4]; \
    _Pragma("unroll") for (int i_ = 0; i_ < 4; ++i_) \
        _Pragma("unroll") for (int j_ = 0; j_ < 4; ++j_) \
            acc[i_][j_] = (f32x4){0.f, 0.f, 0.f, 0.f};

#define MFMA_P(nb) \
    __builtin_amdgcn_s_setprio(1); \
    _Pragma("unroll") for (int m_ = 0; m_ < 4; ++m_) \
        _Pragma("unroll") for (int j_ = 0; j_ < 2; ++j_) \
            _Pragma("unroll") for (int k_ = 0; k_ < 2; ++k_) \
                acc[m_][(nb) + j_] = __builtin_amdgcn_mfma_f32_16x16x32_bf16( \
                    fA[m_][k_], fB[(nb) + j_][k_], acc[m_][(nb) + j_], 0, 0, 0); \
    __builtin_amdgcn_s_setprio(0);

#define GEMM_K_LOOP \
    stageA(0, 0); stageA(0, 1); stageB(0, 0, 0); stageB(0, 0, 1); \
    stageB(0, 1, 0); stageB(0, 1, 1); \
    stageA(1, 0); stageA(1, 1); stageB(1, 0, 0); stageB(1, 0, 1); \
    VMC(6); BAR(); \
    _Pragma("unroll 1") \
    for (int it = 0; it < 8; ++it) { \
        const int t0 = 2 * it, t1 = 2 * it + 1; \
        const bool more = it < 7; \
        bf16x8 fA[4][2], fB[4][2]; \
        _Pragma("unroll") for (int m_ = 0; m_ < 4; ++m_) { fA[m_][0] = rdA(t0, m_, 0); fA[m_][1] = rdA(t0, m_, 1); } \
        _Pragma("unroll") for (int n_ = 0; n_ < 2; ++n_) { fB[n_][0] = rdB(t0, n_, 0); fB[n_][1] = rdB(t0, n_, 1); } \
        stageB(t1, 1, 0); stageB(t1, 1, 1); \
        BAR(); WAIT_LGKM0(); \
        MFMA_P(0); \
        VMC(6); BAR(); \
        _Pragma("unroll") for (int n_ = 0; n_ < 2; ++n_) { fB[2 + n_][0] = rdB(t0, 2 + n_, 0); fB[2 + n_][1] = rdB(t0, 2 + n_, 1); } \
        if (more) { stageA(t0 + 2, 0); stageA(t0 + 2, 1); stageB(t0 + 2, 0, 0); stageB(t0 + 2, 0, 1); } \
        BAR(); WAIT_LGKM0(); \
        MFMA_P(2); \
        if (more) { VMC(6); } else { VMC(2); } \
        BAR(); \
        _Pragma("unroll") for (int m_ = 0; m_ < 4; ++m_) { fA[m_][0] = rdA(t1, m_, 0); fA[m_][1] = rdA(t1, m_, 1); } \
        _Pragma("unroll") for (int n_ = 0; n_ < 2; ++n_) { fB[n_][0] = rdB(t1, n_, 0); fB[n_][1] = rdB(t1, n_, 1); } \
        if (more) { stageB(t0 + 2, 1, 0); stageB(t0 + 2, 1, 1); } \
        BAR(); WAIT_LGKM0(); \
        MFMA_P(0); \
        if (more) { VMC(6); } else { VMC(0); } \
        BAR(); \
        _Pragma("unroll") for (int n_ = 0; n_ < 2; ++n_) { fB[2 + n_][0] = rdB(t1, 2 + n_, 0); fB[2 + n_][1] = rdB(t1, 2 + n_, 1); } \
        if (more) { stageA(t1 + 2, 0); stageA(t1 + 2, 1); stageB(t1 + 2, 0, 0); stageB(t1 + 2, 0, 1); } \
        BAR(); WAIT_LGKM0(); \
        MFMA_P(2); \
        if (more) { VMC(6); } \
        BAR(); \
    }

// ---------------------------------------------------------------------------
// Output projection: A = att2 bf16 [b*16+h][t][64] (gathered), B = Wp^T,
// fp32 out + bias. 128x256 tiles. grid 256 (1D, m fast), block 512.
// ---------------------------------------------------------------------------
__global__ __launch_bounds__(512, 2) void proj_gemm(
    const unsigned short* __restrict__ A,
    const unsigned short* __restrict__ wpt,
    const float* __restrict__ bp,
    float* __restrict__ out)
{
    __shared__ __align__(16) unsigned short sm[49152];   // 96 KiB

    const int bid = blockIdx.x;
    const int m0 = (bid & 63) * 128;
    const int n0 = (bid >> 6) * 256;

    GEMM_CORE_DECLS

    const unsigned short* Ab = A + (size_t)(m0 >> 11) * 16 * 131072 + (size_t)(m0 & 2047) * 64;
    auto stageA = [&](int t, int g) {
        const int rb = w * 16 + g * 8;
        unsigned short* dst = sm + (t & 1) * 24576 + rb * 64;
        GLD(Ab + (size_t)t * 131072 + (rb + rowg) * 64 + swz, dst);
    };
    auto stageB = [&](int t, int R, int g) {
        const int rb = w * 16 + g * 8;
        const int ar0 = (rb >> 5) * 64 + R * 32 + (rb & 31);
        unsigned short* dst = sm + (t & 1) * 24576 + 8192 + ar0 * 64;
        GLD(wpt + (size_t)(n0 + ar0 + rowg) * 1024 + t * 64 + swz, dst);
    };
    auto rdA = [&](int t, int fm, int ks) {
        const int row = wr * 64 + fm * 16 + l15;
        return *(const bf16x8*)&sm[(t & 1) * 24576 + row * 64 + (((ks * 4 + quad) ^ lsw) * 8)];
    };
    auto rdB = [&](int t, int fn, int ks) {
        const int row = wc * 64 + fn * 16 + l15;
        return *(const bf16x8*)&sm[(t & 1) * 24576 + 8192 + row * 64 + (((ks * 4 + quad) ^ lsw) * 8)];
    };

    GEMM_K_LOOP

    #pragma unroll
    for (int fm = 0; fm < 4; ++fm)
        #pragma unroll
        for (int fn = 0; fn < 4; ++fn) {
            int col = n0 + wc * 64 + fn * 16 + l15;
            float bi = bp[col];
            #pragma unroll
            for (int r = 0; r < 4; ++r) {
                int row = m0 + wr * 64 + fm * 16 + quad * 4 + r;
                out[(size_t)row * 1024 + col] = acc[fm][fn][r] + bi;
            }
        }
}

// ---------------------------------------------------------------------------
// Flash attention v6b (unchanged from r13, verified: all dispatches <71.4us).
// KVBLK=64, 32KB LDS, (512,4) non-forcing bound. Block 512 thr = 8 waves =
// 4 q-groups(32q) x 2 key-halves over 128 queries. K/V staged once per block.
// grid (64 bh, 8 pairs), trips 2p+2 legs-paired -> 34/block uniform.
// C/D layout (verified): col=lane&31, row=(reg&3)+8*(reg>>2)+4*(lane>>5).
// ---------------------------------------------------------------------------
__global__ __launch_bounds__(512, 4) void attn_kernel(
    const unsigned short* __restrict__ q, const unsigned short* __restrict__ k,
    const unsigned short* __restrict__ vt, unsigned short* __restrict__ att2)
{
    __shared__ __align__(16) unsigned short KV[2][2][4096];   // [buf][K|V] 32KB

    const int tid = threadIdx.x;
    const int w = tid >> 6, lane = tid & 63;
    const int l31 = lane & 31, h = lane >> 5;
    const int qg2 = w >> 1, ksel = w & 1;     // q-group 0..3, key-half 0..1
    const int bh = blockIdx.x;
    const int rs = l31 & 7;

    const unsigned short* kb = k  + (size_t)bh * 2048 * 64;
    const unsigned short* vb = vt + (size_t)bh * 64 * 2048;

    // ones B-fragment for Osum = P . 1 (row-sums of P in O's C-layout)
    u32x4 onesu; onesu[0] = onesu[1] = onesu[2] = onesu[3] = 0x3F803F80u;
    const bf16x8 bOnes = __builtin_bit_cast(bf16x8, onesu);

    // staging (wave w: rows/d-rows 8w+rg, rg=lane>>3; slot lane&7 <- chunk ^rg)
    const int rg = lane >> 3;
    const size_t kOff = (size_t)(8 * w + rg) * 64 + (size_t)(((lane & 7) ^ rg) * 8);
    const size_t vOff = (size_t)(8 * w + rg) * 2048 + (size_t)(((lane & 7) ^ rg) * 8);

    auto stage = [&](int jt, int buf) {
        GLD(kb + kOff + (size_t)jt * 4096, &KV[buf][0][w * 512]);
        GLD(vb + vOff + jt * 64,           &KV[buf][1][w * 512]);
    };

    for (int leg = 0; leg < 2; ++leg) {
        const int qtile = leg ? (15 - (int)blockIdx.y) : (int)blockIdx.y;
        const int qb0 = qtile * 128;
        const int qmin = qb0 + qg2 * 32, qmax = qmin + 31;
        const int qg = qmin + l31;             // query owned as S^T COLUMN
        const int trips = 2 * qtile + 2;       // 64-key tiles

        // Q B-fragments straight from global: B[k=d][n=query]
        bf16x8 fQ[4];
        {
            const unsigned short* qp = q + ((size_t)bh * 2048 + qg) * 64 + h * 8;
            #pragma unroll
            for (int ks = 0; ks < 4; ++ks) fQ[ks] = *(const bf16x8*)&qp[ks * 16];
        }

        f32x16 O[2], Osum;
        #pragma unroll
        for (int nt = 0; nt < 2; ++nt)
            #pragma unroll
            for (int i = 0; i < 16; ++i) O[nt][i] = 0.f;
        #pragma unroll
        for (int i = 0; i < 16; ++i) Osum[i] = 0.f;

        stage(0, 0);
        VMC(0);
        BAR();

        for (int jt = 0; jt < trips; ++jt) {
            const int buf = jt & 1;
            if (jt + 1 < trips) stage(jt + 1, buf ^ 1);
            const unsigned short* Ks = KV[buf][0];
            const unsigned short* Vs = KV[buf][1];
            const int wk0 = jt * 64 + 32 * ksel;     // wave's 32-key base

            if (wk0 <= qmax) {                       // wave-uniform causal skip
                // QK^T: S = K(32 rows) . Q^T, 4 MFMA over d
                f32x16 S;
                #pragma unroll
                for (int i = 0; i < 16; ++i) S[i] = 0.f;
                __builtin_amdgcn_s_setprio(1);
                {
                    const int row = 32 * ksel + l31;
                    #pragma unroll
                    for (int ks = 0; ks < 4; ++ks) {
                        bf16x8 aK = *(const bf16x8*)&Ks[row * 64 + (((2 * ks + h) ^ rs) * 8)];
                        S = __builtin_amdgcn_mfma_f32_32x32x16_bf16(aK, fQ[ks], S, 0, 0, 0);
                    }
                }
                __builtin_amdgcn_s_setprio(0);

                // softmax (native 2^x): element 4g+r -> key wk0+8g+4h+r
                const bool nm = (wk0 + 31) > qmin;
                unsigned int e0[4], e1[4];
                #pragma unroll
                for (int g = 0; g < 4; ++g) {
                    float p[4];
                    #pragma unroll
                    for (int r = 0; r < 4; ++r) {
                        float pv = ex2(S[4 * g + r]);
                        if (nm) {
                            int key = wk0 + 8 * g + 4 * h + r;
                            if (key > qg) pv = 0.f;
                        }
                        p[r] = pv;
                    }
                    e0[g] = pk2(p[0], p[1]);
                    e1[g] = pk2(p[2], p[3]);
                }

                // PV + Osum: slices s=0,1 cover keys wk0+16s+8h+{0..7}
                __builtin_amdgcn_s_setprio(1);
                #pragma unroll
                for (int s = 0; s < 2; ++s) {
                    unsigned int a = e0[2 * s], b = e0[2 * s + 1];
                    pl32swap(a, b);                       // a={keys+0,+1}, b={+4,+5}
                    unsigned int c2 = e1[2 * s], d2 = e1[2 * s + 1];
                    pl32swap(c2, d2);                     // c2={+2,+3}, d2={+6,+7}
                    u32x4 t; t[0] = a; t[1] = c2; t[2] = b; t[3] = d2;
                    bf16x8 aP = __builtin_bit_cast(bf16x8, t);
                    const int cb = 4 * ksel + 2 * s;      // V chunk c = cb + h
                    #pragma unroll
                    for (int nt = 0; nt < 2; ++nt) {
                        const int drow = nt * 32 + l31;
                        bf16x8 bV = *(const bf16x8*)&Vs[drow * 64 + (((cb + h) ^ rs) * 8)];
                        O[nt] = __builtin_amdgcn_mfma_f32_32x32x16_bf16(aP, bV, O[nt], 0, 0, 0);
                    }
                    Osum = __builtin_amdgcn_mfma_f32_32x32x16_bf16(aP, bOnes, Osum, 0, 0, 0);
                }
                __builtin_amdgcn_s_setprio(0);
            }

            VMC(0);   // next tile landed
            BAR();
        }

        // -------- two-pass merge of key-halves via freed KV LDS (24KB/pass)
        float* Lf = (float*)KV;
        for (int half = 0; half < 2; ++half) {
            __syncthreads();
            float* mb = Lf + (size_t)(qg2 & 1) * 48 * 64;
            if ((qg2 >> 1) == half && ksel) {
                #pragma unroll
                for (int nt = 0; nt < 2; ++nt)
                    #pragma unroll
                    for (int i = 0; i < 16; ++i)
                        mb[(nt * 16 + i) * 64 + lane] = O[nt][i];
                #pragma unroll
                for (int i = 0; i < 16; ++i)
                    mb[(32 + i) * 64 + lane] = Osum[i];
            }
            __syncthreads();
            if ((qg2 >> 1) == half && !ksel) {
                #pragma unroll
                for (int nt = 0; nt < 2; ++nt)
                    #pragma unroll
                    for (int i = 0; i < 16; ++i)
                        O[nt][i] += mb[(nt * 16 + i) * 64 + lane];
                #pragma unroll
                for (int i = 0; i < 16; ++i)
                    Osum[i] += mb[(32 + i) * 64 + lane];

                // O[nt][4g+r]: query row 8g+4h+r, d col nt*32+l31
                unsigned short* ob = att2 + ((size_t)bh * 2048 + qmin) * 64;
                #pragma unroll
                for (int g = 0; g < 4; ++g)
                    #pragma unroll
                    for (int r = 0; r < 4; ++r) {
                        const float iv = 1.f / Osum[4 * g + r];
                        const int qy = 8 * g + 4 * h + r;
                        #pragma unroll
                        for (int nt = 0; nt < 2; ++nt)
                            ob[(size_t)qy * 64 + nt * 32 + l31] = f2bf(O[nt][4 * g + r] * iv);
                    }
            }
        }
        __syncthreads();   // protect merge reads from next leg's staging
    }
}

extern "C" void kernel_launch(void* const* d_in, const int* in_sizes, int n_in,
                              void* d_out, int out_size, void* d_ws, size_t ws_size,
                              hipStream_t stream) {
    const float* x  = (const float*)d_in[0];
    const float* Wq = (const float*)d_in[1];
    const float* Wk = (const float*)d_in[2];
    const float* Wv = (const float*)d_in[3];
    const float* bq = (const float*)d_in[4];
    const float* bk = (const float*)d_in[5];
    const float* bv = (const float*)d_in[6];
    const float* Wp = (const float*)d_in[7];
    const float* bp = (const float*)d_in[8];
    float* out = (float*)d_out;

    const size_t nx = (size_t)B_ * T_ * E_;
    unsigned short* base = (unsigned short*)d_ws;
    unsigned short* xb  = base;
    unsigned short* qb  = xb + nx;
    unsigned short* kb  = qb + nx;
    unsigned short* vtb = kb + nx;
    unsigned short* atb = vtb + nx;          // [bh][t][64]
    unsigned short* wf  = atb + nx;          // [3072][1024]
    unsigned short* wpt = wf + 3072 * 1024;  // [1024][1024]

    prep_kernel<<<9216, 256, 0, stream>>>(x, xb, Wq, Wk, Wv, Wp, wf, wpt);
    qkv_gemm<<<768, 512, 0, stream>>>(xb, wf, bq, bk, bv, qb, kb, vtb);
    attn_kernel<<<dim3(64, 8), 512, 0, stream>>>(qb, kb, vtb, atb);
    proj_gemm<<<256, 512, 0, stream>>>(atb, wpt, bp, out);
}